// Round 8
// baseline (716.065 us; speedup 1.0000x reference)
//
#include <hip/hip_runtime.h>
#include <hip/hip_bf16.h>
#include <stdint.h>

#define NN 100000      // nodes
#define NE 1600000     // edges
#define INF 256        // in feats
#define HF 128         // hidden feats
#define NC 40          // classes
#define NNP 100352     // NN padded to multiple of 512
#define NB (NNP / 512) // 196 scan blocks

typedef unsigned short ushort_t;
typedef unsigned int uint_t;

__device__ __forceinline__ float bflo(uint_t u) {
    union { uint_t i; float f; } v; v.i = u << 16; return v.f;
}
__device__ __forceinline__ float bfhi(uint_t u) {
    union { uint_t i; float f; } v; v.i = u & 0xffff0000u; return v.f;
}
__device__ __forceinline__ uint_t f2bf(float f) {
    __hip_bfloat16 h = __float2bfloat16(f);
    return (uint_t)*reinterpret_cast<ushort_t*>(&h);
}

// ---- degree histograms ----
__global__ void k_deg(const int* __restrict__ src, const int* __restrict__ dst,
                      int* __restrict__ cs, int* __restrict__ cd) {
    int i = blockIdx.x * 256 + threadIdx.x;
    if (i < NE) {
        atomicAdd(&cs[src[i]], 1);
        atomicAdd(&cd[dst[i]], 1);
    }
}

// ---- counts -> rsqrt(max(deg,1)) ----
__global__ void k_isqrt(const int* __restrict__ cs, const int* __restrict__ cd,
                        float* __restrict__ isq_s, float* __restrict__ isq_d) {
    int i = blockIdx.x * 256 + threadIdx.x;
    if (i < NN) {
        isq_s[i] = rsqrtf(fmaxf((float)cs[i], 1.0f));
        isq_d[i] = rsqrtf(fmaxf((float)cd[i], 1.0f));
    }
}

// ---- scan phase A: per-block sums of cd ----
__global__ void k_scanA(const int* __restrict__ cd, int* __restrict__ blk) {
    __shared__ int s[512];
    int i = blockIdx.x * 512 + threadIdx.x;
    s[threadIdx.x] = (i < NN) ? cd[i] : 0;
    __syncthreads();
    for (int off = 256; off > 0; off >>= 1) {
        if (threadIdx.x < (unsigned)off) s[threadIdx.x] += s[threadIdx.x + off];
        __syncthreads();
    }
    if (threadIdx.x == 0) blk[blockIdx.x] = s[0];
}

// ---- scan phase B: exclusive scan of block sums ----
__global__ void k_scanB(int* __restrict__ blk) {
    if (threadIdx.x == 0) {
        int run = 0;
        for (int b = 0; b < NB; ++b) { int t = blk[b]; blk[b] = run; run += t; }
    }
}

// ---- scan phase C: block inclusive scan -> row_ptr (exclusive), cursor ----
__global__ void k_scanC(const int* __restrict__ cd, const int* __restrict__ blk,
                        int* __restrict__ row_ptr, int* __restrict__ cursor) {
    __shared__ int s[512];
    int i = blockIdx.x * 512 + threadIdx.x;
    int v = (i < NN) ? cd[i] : 0;
    s[threadIdx.x] = v;
    __syncthreads();
    for (int off = 1; off < 512; off <<= 1) {
        int t = 0;
        if (threadIdx.x >= (unsigned)off) t = s[threadIdx.x - off];
        __syncthreads();
        s[threadIdx.x] += t;
        __syncthreads();
    }
    int rp = blk[blockIdx.x] + s[threadIdx.x] - v;  // exclusive prefix
    row_ptr[i] = rp;      // row_ptr[NN] == NE
    cursor[i] = rp;
}

// ---- counting-sort fill: src ids grouped by dst ----
__global__ void k_fill(const int* __restrict__ src, const int* __restrict__ dst,
                       int* __restrict__ cursor, int* __restrict__ srcs) {
    int e = blockIdx.x * 256 + threadIdx.x;
    if (e < NE) {
        int d = dst[e];
        int pos = atomicAdd(&cursor[d], 1);
        srcs[pos] = src[e];
    }
}

// ---- GEMM1: H[N,128](bf16) = (X[N,256]fp32 @ W1[256,128]fp32) * isq_s[row] ----
__launch_bounds__(256)
__global__ void k_gemm1(const float* __restrict__ X, const float* __restrict__ W1,
                        const float* __restrict__ isq_s, ushort_t* __restrict__ H) {
    __shared__ float wl[64 * HF];   // 32 KB chunk of W1

    const int col_t = threadIdx.x & 15;
    const int row_t = threadIdx.x >> 4;
    const int c0 = col_t * 8;
    const int r0 = blockIdx.x * 64 + row_t * 4;

    float acc[4][8];
#pragma unroll
    for (int i = 0; i < 4; i++)
#pragma unroll
        for (int j = 0; j < 8; j++) acc[i][j] = 0.0f;

    int rr[4];
#pragma unroll
    for (int i = 0; i < 4; i++) rr[i] = min(r0 + i, NN - 1);

    for (int ch = 0; ch < 4; ++ch) {
        const float4* wg = (const float4*)(W1 + (size_t)ch * 64 * HF);
        for (int t = threadIdx.x; t < 64 * HF / 4; t += 256)
            ((float4*)wl)[t] = wg[t];
        __syncthreads();

        for (int k0 = 0; k0 < 64; k0 += 8) {
            float xf[4][8];
#pragma unroll
            for (int i = 0; i < 4; i++) {
                const float* xp = &X[(size_t)rr[i] * INF + ch * 64 + k0];
                float4 a = *(const float4*)xp;
                float4 b = *(const float4*)(xp + 4);
                xf[i][0] = a.x; xf[i][1] = a.y; xf[i][2] = a.z; xf[i][3] = a.w;
                xf[i][4] = b.x; xf[i][5] = b.y; xf[i][6] = b.z; xf[i][7] = b.w;
            }
#pragma unroll
            for (int kk = 0; kk < 8; kk++) {
                const float* wp = &wl[(k0 + kk) * HF + c0];
                float4 wa = *(const float4*)wp;
                float4 wb = *(const float4*)(wp + 4);
                float wf[8] = { wa.x, wa.y, wa.z, wa.w, wb.x, wb.y, wb.z, wb.w };
#pragma unroll
                for (int i = 0; i < 4; i++)
#pragma unroll
                    for (int j = 0; j < 8; j++)
                        acc[i][j] += xf[i][kk] * wf[j];
            }
        }
        __syncthreads();
    }

#pragma unroll
    for (int i = 0; i < 4; i++) {
        int r = r0 + i;
        if (r < NN) {
            float s = isq_s[r];
            uint_t w0 = f2bf(acc[i][0] * s) | (f2bf(acc[i][1] * s) << 16);
            uint_t w1 = f2bf(acc[i][2] * s) | (f2bf(acc[i][3] * s) << 16);
            uint_t w2 = f2bf(acc[i][4] * s) | (f2bf(acc[i][5] * s) << 16);
            uint_t w3 = f2bf(acc[i][6] * s) | (f2bf(acc[i][7] * s) << 16);
            uint4 o = { w0, w1, w2, w3 };
            *(uint4*)&H[(size_t)r * HF + c0] = o;
        }
    }
}

// ---- fused layer1-aggregate + layer2 GEMM ----
// Half-wave per edge: 32 lanes x uint2 (8B) cover one 256B H row; a wave
// processes 2 edges/step, unrolled x4 => 8 edges in flight.
__launch_bounds__(256)
__global__ void k_agg1_gemm2(const int* __restrict__ row_ptr, const int* __restrict__ srcs,
                             const uint2* __restrict__ H64, const float* __restrict__ isq_d,
                             const float* __restrict__ isq_s, const float* __restrict__ b1,
                             const float* __restrict__ W2, float* __restrict__ H2) {
    __shared__ float w2s[HF * NC];   // 20 KB fp32
    __shared__ float h1s[4][HF];     // 2 KB, one slice per wave
    for (int t = threadIdx.x; t < HF * NC; t += 256) w2s[t] = W2[t];

    const int wv = threadIdx.x >> 6;
    const int lane = threadIdx.x & 63;
    const int half = lane >> 5;      // which edge of the pair
    const int hl = lane & 31;        // feats 4*hl .. 4*hl+3
    const int n = blockIdx.x * 4 + wv;

    if (n < NN) {
        int beg = row_ptr[n], end = row_ptr[n + 1];
        float a0 = 0.f, a1 = 0.f, a2 = 0.f, a3 = 0.f;
        int j = beg;
        for (; j + 8 <= end; j += 8) {
            int j0 = j + half * 4;
            int sA = srcs[j0], sB = srcs[j0 + 1], sC = srcs[j0 + 2], sD = srcs[j0 + 3];
            uint2 v0 = H64[(size_t)sA * 32 + hl];
            uint2 v1 = H64[(size_t)sB * 32 + hl];
            uint2 v2 = H64[(size_t)sC * 32 + hl];
            uint2 v3 = H64[(size_t)sD * 32 + hl];
            a0 += bflo(v0.x) + bflo(v1.x) + bflo(v2.x) + bflo(v3.x);
            a1 += bfhi(v0.x) + bfhi(v1.x) + bfhi(v2.x) + bfhi(v3.x);
            a2 += bflo(v0.y) + bflo(v1.y) + bflo(v2.y) + bflo(v3.y);
            a3 += bfhi(v0.y) + bfhi(v1.y) + bfhi(v2.y) + bfhi(v3.y);
        }
        if (half == 0) {           // tail (< 8 edges) on half 0 only
            for (; j < end; ++j) {
                uint2 v = H64[(size_t)srcs[j] * 32 + hl];
                a0 += bflo(v.x); a1 += bfhi(v.x);
                a2 += bflo(v.y); a3 += bfhi(v.y);
            }
        }
        // combine the two halves (wave-uniform branch above => all lanes here)
        float p0 = __shfl(a0, lane ^ 32);
        float p1 = __shfl(a1, lane ^ 32);
        float p2 = __shfl(a2, lane ^ 32);
        float p3 = __shfl(a3, lane ^ 32);
        if (half == 0) {
            float sc = isq_d[n];
            float4 bv = ((const float4*)b1)[hl];
            h1s[wv][hl * 4 + 0] = fmaxf((a0 + p0) * sc + bv.x, 0.f);
            h1s[wv][hl * 4 + 1] = fmaxf((a1 + p1) * sc + bv.y, 0.f);
            h1s[wv][hl * 4 + 2] = fmaxf((a2 + p2) * sc + bv.z, 0.f);
            h1s[wv][hl * 4 + 3] = fmaxf((a3 + p3) * sc + bv.w, 0.f);
        }
    }
    __syncthreads();   // uniform: covers W2 staging + h1 slices

    if (n < NN && lane < NC) {
        float acc = 0.0f;
#pragma unroll 8
        for (int k = 0; k < HF; ++k)
            acc += h1s[wv][k] * w2s[k * NC + lane];
        H2[(size_t)n * NC + lane] = acc * isq_s[n];
    }
}

// ---- gather2: out = (segsum H2) * isq_d + b2, edge loop unrolled x8 ----
__global__ void k_gather2(const int* __restrict__ row_ptr, const int* __restrict__ srcs,
                          const float* __restrict__ H2, const float* __restrict__ isq_d,
                          const float* __restrict__ b2, float* __restrict__ out) {
    int n = blockIdx.x * 4 + (threadIdx.x >> 6);
    int lane = threadIdx.x & 63;
    if (n >= NN || lane >= NC) return;
    int beg = row_ptr[n], end = row_ptr[n + 1];
    float a = 0.0f;
    int j = beg;
    for (; j + 8 <= end; j += 8) {
        int s0 = srcs[j],     s1 = srcs[j + 1], s2 = srcs[j + 2], s3 = srcs[j + 3];
        int s4 = srcs[j + 4], s5 = srcs[j + 5], s6 = srcs[j + 6], s7 = srcs[j + 7];
        float f0 = H2[(size_t)s0 * NC + lane];
        float f1 = H2[(size_t)s1 * NC + lane];
        float f2 = H2[(size_t)s2 * NC + lane];
        float f3 = H2[(size_t)s3 * NC + lane];
        float f4 = H2[(size_t)s4 * NC + lane];
        float f5 = H2[(size_t)s5 * NC + lane];
        float f6 = H2[(size_t)s6 * NC + lane];
        float f7 = H2[(size_t)s7 * NC + lane];
        a += ((f0 + f1) + (f2 + f3)) + ((f4 + f5) + (f6 + f7));
    }
    for (; j < end; ++j)
        a += H2[(size_t)srcs[j] * NC + lane];
    out[(size_t)n * NC + lane] = a * isq_d[n] + b2[lane];
}

extern "C" void kernel_launch(void* const* d_in, const int* in_sizes, int n_in,
                              void* d_out, int out_size, void* d_ws, size_t ws_size,
                              hipStream_t stream) {
    const float* X  = (const float*)d_in[0];
    const int* src  = (const int*)d_in[1];
    const int* dst  = (const int*)d_in[2];
    const float* W1 = (const float*)d_in[3];
    const float* b1 = (const float*)d_in[4];
    const float* W2 = (const float*)d_in[5];
    const float* b2 = (const float*)d_in[6];
    float* out = (float*)d_out;

    // workspace layout in 4-byte words; peak = 12,502,272 words = 47.7 MiB
    int* w = (int*)d_ws;
    int* cs        = w;                         // NNP  (reused as cursor)
    int* cd        = w + NNP;                   // NNP
    float* isq_s   = (float*)(w + 2 * NNP);     // NNP
    float* isq_d   = (float*)(w + 3 * NNP);     // NNP
    int* row_ptr   = w + 4 * NNP;               // NNP (row_ptr[NN] valid)
    int* blk       = w + 5 * NNP;               // 512
    int* srcs      = w + 5 * NNP + 512;         // NE
    ushort_t* H    = (ushort_t*)(w + 5 * NNP + 512 + NE);        // N*128 bf16 (6.4M words)
    float* H2      = (float*)(w + 5 * NNP + 512 + NE + 6400000); // N*40 fp32 (4M words)
    int* cursor    = cs;                        // alias: cs consumed by k_isqrt

    hipMemsetAsync(cs, 0, 2 * NNP * sizeof(int), stream);

    // CSR build (dst-grouped)
    k_deg  <<<(NE + 255) / 256, 256, 0, stream>>>(src, dst, cs, cd);
    k_isqrt<<<(NN + 255) / 256, 256, 0, stream>>>(cs, cd, isq_s, isq_d);
    k_scanA<<<NB, 512, 0, stream>>>(cd, blk);
    k_scanB<<<1, 64, 0, stream>>>(blk);
    k_scanC<<<NB, 512, 0, stream>>>(cd, blk, row_ptr, cursor);
    k_fill <<<(NE + 255) / 256, 256, 0, stream>>>(src, dst, cursor, srcs);

    // layer 1 GEMM
    k_gemm1<<<(NN + 63) / 64, 256, 0, stream>>>(X, W1, isq_s, H);

    // fused: layer-1 aggregate + bias/relu + layer-2 GEMM
    k_agg1_gemm2<<<(NN + 3) / 4, 256, 0, stream>>>(row_ptr, srcs, (const uint2*)H,
                                                   isq_d, isq_s, b1, W2, H2);

    // layer-2 aggregate + bias -> fp32 out
    k_gather2<<<(NN + 3) / 4, 256, 0, stream>>>(row_ptr, srcs, H2, isq_d, b2, out);
}

// Round 9
// 650.440 us; speedup vs baseline: 1.1009x; 1.1009x over previous
//
#include <hip/hip_runtime.h>
#include <hip/hip_bf16.h>
#include <stdint.h>

#define NN 100000      // nodes
#define NE 1600000     // edges
#define INF 256        // in feats
#define HF 128         // hidden feats
#define NC 40          // classes
#define NNP 100352     // NN padded to multiple of 512
#define NB (NNP / 512) // 196 scan blocks

typedef unsigned short ushort_t;
typedef unsigned int uint_t;
typedef __attribute__((ext_vector_type(8))) short short8;   // 8 bf16 (4 VGPR)
typedef __attribute__((ext_vector_type(4))) float f32x4;

__device__ __forceinline__ float bflo(uint_t u) {
    union { uint_t i; float f; } v; v.i = u << 16; return v.f;
}
__device__ __forceinline__ float bfhi(uint_t u) {
    union { uint_t i; float f; } v; v.i = u & 0xffff0000u; return v.f;
}
__device__ __forceinline__ uint_t f2bf(float f) {
    __hip_bfloat16 h = __float2bfloat16(f);
    return (uint_t)*reinterpret_cast<ushort_t*>(&h);
}

// ---- degree histograms ----
__global__ void k_deg(const int* __restrict__ src, const int* __restrict__ dst,
                      int* __restrict__ cs, int* __restrict__ cd) {
    int i = blockIdx.x * 256 + threadIdx.x;
    if (i < NE) {
        atomicAdd(&cs[src[i]], 1);
        atomicAdd(&cd[dst[i]], 1);
    }
}

// ---- counts -> rsqrt(max(deg,1)) ----
__global__ void k_isqrt(const int* __restrict__ cs, const int* __restrict__ cd,
                        float* __restrict__ isq_s, float* __restrict__ isq_d) {
    int i = blockIdx.x * 256 + threadIdx.x;
    if (i < NN) {
        isq_s[i] = rsqrtf(fmaxf((float)cs[i], 1.0f));
        isq_d[i] = rsqrtf(fmaxf((float)cd[i], 1.0f));
    }
}

// ---- scan phase A: per-block sums of cd ----
__global__ void k_scanA(const int* __restrict__ cd, int* __restrict__ blk) {
    __shared__ int s[512];
    int i = blockIdx.x * 512 + threadIdx.x;
    s[threadIdx.x] = (i < NN) ? cd[i] : 0;
    __syncthreads();
    for (int off = 256; off > 0; off >>= 1) {
        if (threadIdx.x < (unsigned)off) s[threadIdx.x] += s[threadIdx.x + off];
        __syncthreads();
    }
    if (threadIdx.x == 0) blk[blockIdx.x] = s[0];
}

// ---- scan phase B: exclusive scan of block sums ----
__global__ void k_scanB(int* __restrict__ blk) {
    if (threadIdx.x == 0) {
        int run = 0;
        for (int b = 0; b < NB; ++b) { int t = blk[b]; blk[b] = run; run += t; }
    }
}

// ---- scan phase C: block inclusive scan -> row_ptr (exclusive), cursor ----
__global__ void k_scanC(const int* __restrict__ cd, const int* __restrict__ blk,
                        int* __restrict__ row_ptr, int* __restrict__ cursor) {
    __shared__ int s[512];
    int i = blockIdx.x * 512 + threadIdx.x;
    int v = (i < NN) ? cd[i] : 0;
    s[threadIdx.x] = v;
    __syncthreads();
    for (int off = 1; off < 512; off <<= 1) {
        int t = 0;
        if (threadIdx.x >= (unsigned)off) t = s[threadIdx.x - off];
        __syncthreads();
        s[threadIdx.x] += t;
        __syncthreads();
    }
    int rp = blk[blockIdx.x] + s[threadIdx.x] - v;  // exclusive prefix
    row_ptr[i] = rp;      // row_ptr[NN] == NE
    cursor[i] = rp;
}

// ---- counting-sort fill: src ids grouped by dst ----
__global__ void k_fill(const int* __restrict__ src, const int* __restrict__ dst,
                       int* __restrict__ cursor, int* __restrict__ srcs) {
    int e = blockIdx.x * 256 + threadIdx.x;
    if (e < NE) {
        int d = dst[e];
        int pos = atomicAdd(&cursor[d], 1);
        srcs[pos] = src[e];
    }
}

// ---- W1 -> fragment-major bf16 (one-time, 32K elems) ----
// B-frag for (ks,ct): lane(q*16+ln) reads 16B at ((ks*8+ct)*64 + lane)*16B
// element (k,n): ks=k/32, q=(k/8)%4, j=k%8, ct=n/16, ln=n%16
// off = (((ks*8+ct)*4+q)*16+ln)*8 + j
__global__ void k_w1conv(const float* __restrict__ W1, ushort_t* __restrict__ W1f) {
    int i = blockIdx.x * 256 + threadIdx.x;
    if (i < INF * HF) {
        int k = i >> 7, n = i & 127;
        int ks = k >> 5, q = (k >> 3) & 3, j = k & 7;
        int ct = n >> 4, ln = n & 15;
        int off = (((ks * 8 + ct) * 4 + q) * 16 + ln) * 8 + j;
        W1f[off] = (ushort_t)f2bf(W1[i]);
    }
}

// ---- GEMM1 (MFMA): H[N,128](bf16) = (X[N,256] @ W1) * isq_s[row] ----
// 4 waves/block, wave handles 16 rows x 128 cols; no LDS, no barriers.
__launch_bounds__(256)
__global__ void k_gemm1(const float* __restrict__ X, const ushort_t* __restrict__ W1f,
                        const float* __restrict__ isq_s, ushort_t* __restrict__ H) {
    const int wv = threadIdx.x >> 6;
    const int lane = threadIdx.x & 63;
    const int ln = lane & 15;
    const int q  = lane >> 4;
    const int r0 = blockIdx.x * 64 + wv * 16;
    const int rm = min(r0 + ln, NN - 1);     // A row for this lane (m = ln)

    f32x4 acc[8];
#pragma unroll
    for (int ct = 0; ct < 8; ++ct) acc[ct] = (f32x4){0.f, 0.f, 0.f, 0.f};

    const float* xp = &X[(size_t)rm * INF + q * 8];
    const uint4* wf = (const uint4*)W1f;

    for (int ks = 0; ks < 8; ++ks) {
        // A-frag: X[rm][ks*32 + q*8 .. +8) fp32 -> bf16
        float4 xa = *(const float4*)xp;
        float4 xb = *(const float4*)(xp + 4);
        xp += 32;
        short8 af;
        af[0] = (short)f2bf(xa.x); af[1] = (short)f2bf(xa.y);
        af[2] = (short)f2bf(xa.z); af[3] = (short)f2bf(xa.w);
        af[4] = (short)f2bf(xb.x); af[5] = (short)f2bf(xb.y);
        af[6] = (short)f2bf(xb.z); af[7] = (short)f2bf(xb.w);
#pragma unroll
        for (int ct = 0; ct < 8; ++ct) {
            union { uint4 u; short8 s; } bv;
            bv.u = wf[(size_t)(ks * 8 + ct) * 64 + lane];
            acc[ct] = __builtin_amdgcn_mfma_f32_16x16x32_bf16(af, bv.s, acc[ct], 0, 0, 0);
        }
    }

    // epilogue: D row = r0 + q*4 + reg, col = ct*16 + ln
#pragma unroll
    for (int reg = 0; reg < 4; ++reg) {
        int r = r0 + q * 4 + reg;
        if (r < NN) {
            float s = isq_s[r];
#pragma unroll
            for (int ct = 0; ct < 8; ++ct)
                H[(size_t)r * HF + ct * 16 + ln] = (ushort_t)f2bf(acc[ct][reg] * s);
        }
    }
}

// ---- fused layer1-aggregate + layer2 GEMM (R7 form), H2 out as bf16 ----
__launch_bounds__(256)
__global__ void k_agg1_gemm2(const int* __restrict__ row_ptr, const int* __restrict__ srcs,
                             const uint_t* __restrict__ H32, const float* __restrict__ isq_d,
                             const float* __restrict__ isq_s, const float* __restrict__ b1,
                             const float* __restrict__ W2, ushort_t* __restrict__ H2b) {
    __shared__ float w2s[HF * NC];   // 20 KB fp32
    __shared__ float h1s[4][HF];     // 2 KB, one slice per wave
    for (int t = threadIdx.x; t < HF * NC; t += 256) w2s[t] = W2[t];

    const int wv = threadIdx.x >> 6;
    const int lane = threadIdx.x & 63;
    const int n = blockIdx.x * 4 + wv;

    if (n < NN) {
        int beg = row_ptr[n], end = row_ptr[n + 1];
        float a0 = 0.0f, a1 = 0.0f;
        int j = beg;
        for (; j + 4 <= end; j += 4) {
            int s0 = srcs[j], s1 = srcs[j + 1], s2 = srcs[j + 2], s3 = srcs[j + 3];
            uint_t v0 = H32[(size_t)s0 * 64 + lane];
            uint_t v1 = H32[(size_t)s1 * 64 + lane];
            uint_t v2 = H32[(size_t)s2 * 64 + lane];
            uint_t v3 = H32[(size_t)s3 * 64 + lane];
            a0 += bflo(v0) + bflo(v1) + bflo(v2) + bflo(v3);
            a1 += bfhi(v0) + bfhi(v1) + bfhi(v2) + bfhi(v3);
        }
        for (; j < end; ++j) {
            uint_t v = H32[(size_t)srcs[j] * 64 + lane];
            a0 += bflo(v);
            a1 += bfhi(v);
        }
        float sc = isq_d[n];
        float2 bv = ((const float2*)b1)[lane];
        h1s[wv][lane * 2]     = fmaxf(a0 * sc + bv.x, 0.0f);
        h1s[wv][lane * 2 + 1] = fmaxf(a1 * sc + bv.y, 0.0f);
    }
    __syncthreads();   // uniform: covers W2 staging + h1 slices

    if (n < NN && lane < NC) {
        float acc = 0.0f;
#pragma unroll 8
        for (int k = 0; k < HF; ++k)
            acc += h1s[wv][k] * w2s[k * NC + lane];
        H2b[(size_t)n * NC + lane] = (ushort_t)f2bf(acc * isq_s[n]);
    }
}

// ---- gather2: out = (segsum H2b) * isq_d + b2 ; 20 lanes x uint (2 bf16) ----
__global__ void k_gather2(const int* __restrict__ row_ptr, const int* __restrict__ srcs,
                          const uint_t* __restrict__ H2b32, const float* __restrict__ isq_d,
                          const float* __restrict__ b2, float* __restrict__ out) {
    int n = blockIdx.x * 4 + (threadIdx.x >> 6);
    int lane = threadIdx.x & 63;
    if (n >= NN || lane >= NC / 2) return;
    int beg = row_ptr[n], end = row_ptr[n + 1];
    float a0 = 0.0f, a1 = 0.0f;
    int j = beg;
    for (; j + 8 <= end; j += 8) {
        int s0 = srcs[j],     s1 = srcs[j + 1], s2 = srcs[j + 2], s3 = srcs[j + 3];
        int s4 = srcs[j + 4], s5 = srcs[j + 5], s6 = srcs[j + 6], s7 = srcs[j + 7];
        uint_t v0 = H2b32[(size_t)s0 * 20 + lane];
        uint_t v1 = H2b32[(size_t)s1 * 20 + lane];
        uint_t v2 = H2b32[(size_t)s2 * 20 + lane];
        uint_t v3 = H2b32[(size_t)s3 * 20 + lane];
        uint_t v4 = H2b32[(size_t)s4 * 20 + lane];
        uint_t v5 = H2b32[(size_t)s5 * 20 + lane];
        uint_t v6 = H2b32[(size_t)s6 * 20 + lane];
        uint_t v7 = H2b32[(size_t)s7 * 20 + lane];
        a0 += ((bflo(v0) + bflo(v1)) + (bflo(v2) + bflo(v3))) +
              ((bflo(v4) + bflo(v5)) + (bflo(v6) + bflo(v7)));
        a1 += ((bfhi(v0) + bfhi(v1)) + (bfhi(v2) + bfhi(v3))) +
              ((bfhi(v4) + bfhi(v5)) + (bfhi(v6) + bfhi(v7)));
    }
    for (; j < end; ++j) {
        uint_t v = H2b32[(size_t)srcs[j] * 20 + lane];
        a0 += bflo(v);
        a1 += bfhi(v);
    }
    float sc = isq_d[n];
    float2 bv = *(const float2*)&b2[lane * 2];
    float2 o = { a0 * sc + bv.x, a1 * sc + bv.y };
    *(float2*)&out[(size_t)n * NC + lane * 2] = o;
}

extern "C" void kernel_launch(void* const* d_in, const int* in_sizes, int n_in,
                              void* d_out, int out_size, void* d_ws, size_t ws_size,
                              hipStream_t stream) {
    const float* X  = (const float*)d_in[0];
    const int* src  = (const int*)d_in[1];
    const int* dst  = (const int*)d_in[2];
    const float* W1 = (const float*)d_in[3];
    const float* b1 = (const float*)d_in[4];
    const float* W2 = (const float*)d_in[5];
    const float* b2 = (const float*)d_in[6];
    float* out = (float*)d_out;

    // workspace layout in 4-byte words; peak = 10,518,656 words = 40.1 MiB
    int* w = (int*)d_ws;
    int* cs        = w;                         // NNP  (reused as cursor)
    int* cd        = w + NNP;                   // NNP
    float* isq_s   = (float*)(w + 2 * NNP);     // NNP
    float* isq_d   = (float*)(w + 3 * NNP);     // NNP
    int* row_ptr   = w + 4 * NNP;               // NNP (row_ptr[NN] valid)
    int* blk       = w + 5 * NNP;               // 512
    ushort_t* W1f  = (ushort_t*)(w + 5 * NNP + 512);             // 32768 bf16 (16384 words)
    int* srcs      = w + 5 * NNP + 512 + 16384; // NE
    ushort_t* H    = (ushort_t*)(w + 5 * NNP + 512 + 16384 + NE);           // N*128 bf16
    ushort_t* H2b  = (ushort_t*)(w + 5 * NNP + 512 + 16384 + NE + 6400000); // N*40 bf16
    int* cursor    = cs;                        // alias: cs consumed by k_isqrt

    hipMemsetAsync(cs, 0, 2 * NNP * sizeof(int), stream);

    // one-time W1 -> fragment-major bf16
    k_w1conv<<<(INF * HF + 255) / 256, 256, 0, stream>>>(W1, W1f);

    // CSR build (dst-grouped)
    k_deg  <<<(NE + 255) / 256, 256, 0, stream>>>(src, dst, cs, cd);
    k_isqrt<<<(NN + 255) / 256, 256, 0, stream>>>(cs, cd, isq_s, isq_d);
    k_scanA<<<NB, 512, 0, stream>>>(cd, blk);
    k_scanB<<<1, 64, 0, stream>>>(blk);
    k_scanC<<<NB, 512, 0, stream>>>(cd, blk, row_ptr, cursor);
    k_fill <<<(NE + 255) / 256, 256, 0, stream>>>(src, dst, cursor, srcs);

    // layer 1 GEMM (MFMA)
    k_gemm1<<<(NN + 63) / 64, 256, 0, stream>>>(X, W1f, isq_s, H);

    // fused: layer-1 aggregate + bias/relu + layer-2 GEMM -> bf16 H2
    k_agg1_gemm2<<<(NN + 3) / 4, 256, 0, stream>>>(row_ptr, srcs, (const uint_t*)H,
                                                   isq_d, isq_s, b1, W2, H2b);

    // layer-2 aggregate + bias -> fp32 out
    k_gather2<<<(NN + 3) / 4, 256, 0, stream>>>(row_ptr, srcs, (const uint_t*)H2b,
                                                isq_d, b2, out);
}

// Round 10
// 621.664 us; speedup vs baseline: 1.1519x; 1.0463x over previous
//
#include <hip/hip_runtime.h>
#include <hip/hip_bf16.h>
#include <stdint.h>

#define NN 100000      // nodes
#define NE 1600000     // edges
#define INF 256        // in feats
#define HF 128         // hidden feats
#define NC 40          // classes
#define NNP 100352     // NN padded to multiple of 512
#define NB (NNP / 512) // 196 scan blocks

typedef unsigned short ushort_t;
typedef unsigned int uint_t;
typedef __attribute__((ext_vector_type(8))) short short8;   // 8 bf16 (4 VGPR)
typedef __attribute__((ext_vector_type(4))) float f32x4;

__device__ __forceinline__ float bflo(uint_t u) {
    union { uint_t i; float f; } v; v.i = u << 16; return v.f;
}
__device__ __forceinline__ float bfhi(uint_t u) {
    union { uint_t i; float f; } v; v.i = u & 0xffff0000u; return v.f;
}
__device__ __forceinline__ uint_t f2bf(float f) {
    __hip_bfloat16 h = __float2bfloat16(f);
    return (uint_t)*reinterpret_cast<ushort_t*>(&h);
}

// ---- degree histograms + one-time W1 -> fragment-major bf16 ----
// W1f layout: element (k,n) -> (((ks*8+ct)*4+q)*16+ln)*8 + j
// with ks=k/32, q=(k/8)%4, j=k%8, ct=n/16, ln=n%16
__global__ void k_deg(const int* __restrict__ src, const int* __restrict__ dst,
                      int* __restrict__ cs, int* __restrict__ cd,
                      const float* __restrict__ W1, ushort_t* __restrict__ W1f) {
    int i = blockIdx.x * 256 + threadIdx.x;
    if (i < NE) {
        atomicAdd(&cs[src[i]], 1);
        atomicAdd(&cd[dst[i]], 1);
    }
    if (i < INF * HF) {
        int k = i >> 7, n = i & 127;
        int ks = k >> 5, q = (k >> 3) & 3, j = k & 7;
        int ct = n >> 4, ln = n & 15;
        int off = (((ks * 8 + ct) * 4 + q) * 16 + ln) * 8 + j;
        W1f[off] = (ushort_t)f2bf(W1[i]);
    }
}

// ---- scan phase A: per-block sums of cd ----
__global__ void k_scanA(const int* __restrict__ cd, int* __restrict__ blk) {
    __shared__ int s[512];
    int i = blockIdx.x * 512 + threadIdx.x;
    s[threadIdx.x] = (i < NN) ? cd[i] : 0;
    __syncthreads();
    for (int off = 256; off > 0; off >>= 1) {
        if (threadIdx.x < (unsigned)off) s[threadIdx.x] += s[threadIdx.x + off];
        __syncthreads();
    }
    if (threadIdx.x == 0) blk[blockIdx.x] = s[0];
}

// ---- scan phase B: exclusive scan of block sums ----
__global__ void k_scanB(int* __restrict__ blk) {
    if (threadIdx.x == 0) {
        int run = 0;
        for (int b = 0; b < NB; ++b) { int t = blk[b]; blk[b] = run; run += t; }
    }
}

// ---- scan phase C: row_ptr/cursor + isqrt norms (fused) ----
__global__ void k_scanC(const int* __restrict__ cd, const int* __restrict__ blk,
                        const int* __restrict__ cs,
                        int* __restrict__ row_ptr, int* __restrict__ cursor,
                        float* __restrict__ isq_s, float* __restrict__ isq_d) {
    __shared__ int s[512];
    int i = blockIdx.x * 512 + threadIdx.x;
    int v = (i < NN) ? cd[i] : 0;
    s[threadIdx.x] = v;
    __syncthreads();
    for (int off = 1; off < 512; off <<= 1) {
        int t = 0;
        if (threadIdx.x >= (unsigned)off) t = s[threadIdx.x - off];
        __syncthreads();
        s[threadIdx.x] += t;
        __syncthreads();
    }
    int rp = blk[blockIdx.x] + s[threadIdx.x] - v;  // exclusive prefix
    row_ptr[i] = rp;      // row_ptr[NN] == NE
    // norms (before cursor write: cursor aliases cs, read cs first)
    float fs = rsqrtf(fmaxf((float)cs[i], 1.0f));
    float fd = rsqrtf(fmaxf((float)v, 1.0f));
    cursor[i] = rp;
    isq_s[i] = fs;
    isq_d[i] = fd;
}

// ---- counting-sort fill: src ids grouped by dst ----
__global__ void k_fill(const int* __restrict__ src, const int* __restrict__ dst,
                       int* __restrict__ cursor, int* __restrict__ srcs) {
    int e = blockIdx.x * 256 + threadIdx.x;
    if (e < NE) {
        int d = dst[e];
        int pos = atomicAdd(&cursor[d], 1);
        srcs[pos] = src[e];
    }
}

// ---- GEMM1 (MFMA): H[N,128](bf16) = (X[N,256] @ W1) * isq_s[row] ----
__launch_bounds__(256)
__global__ void k_gemm1(const float* __restrict__ X, const ushort_t* __restrict__ W1f,
                        const float* __restrict__ isq_s, ushort_t* __restrict__ H) {
    const int wv = threadIdx.x >> 6;
    const int lane = threadIdx.x & 63;
    const int ln = lane & 15;
    const int q  = lane >> 4;
    const int r0 = blockIdx.x * 64 + wv * 16;
    const int rm = min(r0 + ln, NN - 1);     // A row for this lane (m = ln)

    f32x4 acc[8];
#pragma unroll
    for (int ct = 0; ct < 8; ++ct) acc[ct] = (f32x4){0.f, 0.f, 0.f, 0.f};

    const float* xp = &X[(size_t)rm * INF + q * 8];
    const uint4* wf = (const uint4*)W1f;

    for (int ks = 0; ks < 8; ++ks) {
        float4 xa = *(const float4*)xp;
        float4 xb = *(const float4*)(xp + 4);
        xp += 32;
        short8 af;
        af[0] = (short)f2bf(xa.x); af[1] = (short)f2bf(xa.y);
        af[2] = (short)f2bf(xa.z); af[3] = (short)f2bf(xa.w);
        af[4] = (short)f2bf(xb.x); af[5] = (short)f2bf(xb.y);
        af[6] = (short)f2bf(xb.z); af[7] = (short)f2bf(xb.w);
#pragma unroll
        for (int ct = 0; ct < 8; ++ct) {
            union { uint4 u; short8 s; } bv;
            bv.u = wf[(size_t)(ks * 8 + ct) * 64 + lane];
            acc[ct] = __builtin_amdgcn_mfma_f32_16x16x32_bf16(af, bv.s, acc[ct], 0, 0, 0);
        }
    }

#pragma unroll
    for (int reg = 0; reg < 4; ++reg) {
        int r = r0 + q * 4 + reg;
        if (r < NN) {
            float s = isq_s[r];
#pragma unroll
            for (int ct = 0; ct < 8; ++ct)
                H[(size_t)r * HF + ct * 16 + ln] = (ushort_t)f2bf(acc[ct][reg] * s);
        }
    }
}

// ---- fused layer1-aggregate + layer2 GEMM (R7 form), H2 out as bf16 ----
__launch_bounds__(256)
__global__ void k_agg1_gemm2(const int* __restrict__ row_ptr, const int* __restrict__ srcs,
                             const uint_t* __restrict__ H32, const float* __restrict__ isq_d,
                             const float* __restrict__ isq_s, const float* __restrict__ b1,
                             const float* __restrict__ W2, ushort_t* __restrict__ H2b) {
    __shared__ float w2s[HF * NC];   // 20 KB fp32
    __shared__ float h1s[4][HF];     // 2 KB, one slice per wave
    for (int t = threadIdx.x; t < HF * NC; t += 256) w2s[t] = W2[t];

    const int wv = threadIdx.x >> 6;
    const int lane = threadIdx.x & 63;
    const int n = blockIdx.x * 4 + wv;

    if (n < NN) {
        int beg = row_ptr[n], end = row_ptr[n + 1];
        float a0 = 0.0f, a1 = 0.0f;
        int j = beg;
        for (; j + 4 <= end; j += 4) {
            int s0 = srcs[j], s1 = srcs[j + 1], s2 = srcs[j + 2], s3 = srcs[j + 3];
            uint_t v0 = H32[(size_t)s0 * 64 + lane];
            uint_t v1 = H32[(size_t)s1 * 64 + lane];
            uint_t v2 = H32[(size_t)s2 * 64 + lane];
            uint_t v3 = H32[(size_t)s3 * 64 + lane];
            a0 += bflo(v0) + bflo(v1) + bflo(v2) + bflo(v3);
            a1 += bfhi(v0) + bfhi(v1) + bfhi(v2) + bfhi(v3);
        }
        for (; j < end; ++j) {
            uint_t v = H32[(size_t)srcs[j] * 64 + lane];
            a0 += bflo(v);
            a1 += bfhi(v);
        }
        float sc = isq_d[n];
        float2 bv = ((const float2*)b1)[lane];
        h1s[wv][lane * 2]     = fmaxf(a0 * sc + bv.x, 0.0f);
        h1s[wv][lane * 2 + 1] = fmaxf(a1 * sc + bv.y, 0.0f);
    }
    __syncthreads();   // uniform: covers W2 staging + h1 slices

    if (n < NN && lane < NC) {
        float acc = 0.0f;
#pragma unroll 8
        for (int k = 0; k < HF; ++k)
            acc += h1s[wv][k] * w2s[k * NC + lane];
        H2b[(size_t)n * NC + lane] = (ushort_t)f2bf(acc * isq_s[n]);
    }
}

// ---- gather2 v2: 10 lanes x uint2 per edge, 6 edges per wave in parallel ----
__global__ void k_gather2(const int* __restrict__ row_ptr, const int* __restrict__ srcs,
                          const uint2* __restrict__ H2b2, const float* __restrict__ isq_d,
                          const float* __restrict__ b2, float* __restrict__ out) {
    __shared__ float4 pt[4][64];     // 4 KB partials
    const int wv = threadIdx.x >> 6;
    const int lane = threadIdx.x & 63;
    const int grp = lane / 10;       // 0..5 active edge slots, 6 = idle lanes 60-63
    const int gl  = lane - grp * 10; // uint2 index within the 80B row
    const int n = blockIdx.x * 4 + wv;

    float a0 = 0.f, a1 = 0.f, a2 = 0.f, a3 = 0.f;
    if (n < NN && grp < 6) {
        int beg = row_ptr[n], end = row_ptr[n + 1];
        int j = beg;
        for (; j + 12 <= end; j += 12) {           // 12 edges in flight
            int eA = j + grp, eB = j + 6 + grp;
            uint2 vA = H2b2[(size_t)srcs[eA] * 10 + gl];
            uint2 vB = H2b2[(size_t)srcs[eB] * 10 + gl];
            a0 += bflo(vA.x) + bflo(vB.x);
            a1 += bfhi(vA.x) + bfhi(vB.x);
            a2 += bflo(vA.y) + bflo(vB.y);
            a3 += bfhi(vA.y) + bfhi(vB.y);
        }
        if (j + 6 <= end) {
            uint2 v = H2b2[(size_t)srcs[j + grp] * 10 + gl];
            a0 += bflo(v.x); a1 += bfhi(v.x);
            a2 += bflo(v.y); a3 += bfhi(v.y);
            j += 6;
        }
        int r = end - j;                            // 0..5 tail edges
        if (grp < r) {
            uint2 v = H2b2[(size_t)srcs[j + grp] * 10 + gl];
            a0 += bflo(v.x); a1 += bfhi(v.x);
            a2 += bflo(v.y); a3 += bfhi(v.y);
        }
    }
    pt[wv][lane] = (float4){a0, a1, a2, a3};
    __syncthreads();

    if (n < NN && lane < 10) {
        float4 s = pt[wv][lane];
#pragma unroll
        for (int g = 1; g < 6; ++g) {
            float4 t = pt[wv][g * 10 + lane];
            s.x += t.x; s.y += t.y; s.z += t.z; s.w += t.w;
        }
        float sc = isq_d[n];
        float4 bv = *(const float4*)&b2[lane * 4];
        float4 o = { s.x * sc + bv.x, s.y * sc + bv.y,
                     s.z * sc + bv.z, s.w * sc + bv.w };
        *(float4*)&out[(size_t)n * NC + lane * 4] = o;
    }
}

extern "C" void kernel_launch(void* const* d_in, const int* in_sizes, int n_in,
                              void* d_out, int out_size, void* d_ws, size_t ws_size,
                              hipStream_t stream) {
    const float* X  = (const float*)d_in[0];
    const int* src  = (const int*)d_in[1];
    const int* dst  = (const int*)d_in[2];
    const float* W1 = (const float*)d_in[3];
    const float* b1 = (const float*)d_in[4];
    const float* W2 = (const float*)d_in[5];
    const float* b2 = (const float*)d_in[6];
    float* out = (float*)d_out;

    // workspace layout in 4-byte words; peak = 10,518,656 words = 40.1 MiB
    int* w = (int*)d_ws;
    int* cs        = w;                         // NNP  (reused as cursor)
    int* cd        = w + NNP;                   // NNP
    float* isq_s   = (float*)(w + 2 * NNP);     // NNP
    float* isq_d   = (float*)(w + 3 * NNP);     // NNP
    int* row_ptr   = w + 4 * NNP;               // NNP (row_ptr[NN] valid)
    int* blk       = w + 5 * NNP;               // 512
    ushort_t* W1f  = (ushort_t*)(w + 5 * NNP + 512);             // 32768 bf16
    int* srcs      = w + 5 * NNP + 512 + 16384; // NE
    ushort_t* H    = (ushort_t*)(w + 5 * NNP + 512 + 16384 + NE);           // N*128 bf16
    ushort_t* H2b  = (ushort_t*)(w + 5 * NNP + 512 + 16384 + NE + 6400000); // N*40 bf16
    int* cursor    = cs;                        // alias: cs consumed inside k_scanC

    hipMemsetAsync(cs, 0, 2 * NNP * sizeof(int), stream);

    // CSR build (dst-grouped) + W1 fragment conversion
    k_deg  <<<(NE + 255) / 256, 256, 0, stream>>>(src, dst, cs, cd, W1, W1f);
    k_scanA<<<NB, 512, 0, stream>>>(cd, blk);
    k_scanB<<<1, 64, 0, stream>>>(blk);
    k_scanC<<<NB, 512, 0, stream>>>(cd, blk, cs, row_ptr, cursor, isq_s, isq_d);
    k_fill <<<(NE + 255) / 256, 256, 0, stream>>>(src, dst, cursor, srcs);

    // layer 1 GEMM (MFMA)
    k_gemm1<<<(NN + 63) / 64, 256, 0, stream>>>(X, W1f, isq_s, H);

    // fused: layer-1 aggregate + bias/relu + layer-2 GEMM -> bf16 H2
    k_agg1_gemm2<<<(NN + 3) / 4, 256, 0, stream>>>(row_ptr, srcs, (const uint_t*)H,
                                                   isq_d, isq_s, b1, W2, H2b);

    // layer-2 aggregate + bias -> fp32 out
    k_gather2<<<(NN + 3) / 4, 256, 0, stream>>>(row_ptr, srcs, (const uint2*)H2b,
                                                isq_d, b2, out);
}